// Round 5
// baseline (203.226 us; speedup 1.0000x reference)
//
#include <hip/hip_runtime.h>
#include <math.h>

// PeakAreaFloodLoss: B=2048 rows, S=8192 cols, fp32 p/t + i32 mask -> scalar.
// Round-3 post-mortem: dur invariant to occupancy, block size, and HBM-vs-L3
// data source => fixed ~37ns-per-block serialization (2048 same-address
// atomics and/or WG dispatch). Round 4/5: 512 blocks x 4 rows each, ZERO
// atomics (contention-free partials in d_ws + tiny reduce kernel), no memset.

#define S_LEN 8192
#define BLK   1024
#define NWAVE (BLK / 64)          // 16
#define VEC   (S_LEN / 4 / BLK)   // 2 float4 per thread = 8 elements
#define ROWS_PER_BLK 4

__device__ __forceinline__ float waveSum(float x) {
    #pragma unroll
    for (int o = 32; o > 0; o >>= 1) x += __shfl_down(x, o, 64);
    return x;
}
__device__ __forceinline__ float waveMax(float x) {
    #pragma unroll
    for (int o = 32; o > 0; o >>= 1) x = fmaxf(x, __shfl_down(x, o, 64));
    return x;
}

__global__ __launch_bounds__(BLK) void flood_loss_rows(
    const float* __restrict__ P, const float* __restrict__ T,
    const int* __restrict__ M, float* __restrict__ partial)
{
    __shared__ float red[NWAVE][4];

    const int tid  = threadIdx.x;
    const int wid  = tid >> 6;
    const int lane = tid & 63;

    float losssum = 0.f; // only tid 0's copy matters

    for (int r = 0; r < ROWS_PER_BLK; ++r) {
        const size_t row  = (size_t)blockIdx.x * ROWS_PER_BLK + r;
        const size_t base = row * S_LEN;
        const float4* __restrict__ P4 = (const float4*)(P + base);
        const float4* __restrict__ T4 = (const float4*)(T + base);
        const int4*   __restrict__ M4 = (const int4*)(M + base);

        // ---- pass 1: coalesced sweep; stats + pinned register staging ----
        float tenc[VEC * 4]; // t, invalid -> -INF (one-compare 'high' test)
        float d2v [VEC * 4]; // valid ? (p-t)^2 : 0
        float ssq = 0.f, fn = 0.f;
        float tpk = -INFINITY, ppk = -INFINITY;

        #pragma unroll
        for (int it = 0; it < VEC; ++it) {
            const int v = it * BLK + tid;      // float4 index, coalesced
            float4 p4 = P4[v];
            float4 t4 = T4[v];
            int4   m4 = M4[v];
            float pe[4] = {p4.x, p4.y, p4.z, p4.w};
            float te[4] = {t4.x, t4.y, t4.z, t4.w};
            int   me[4] = {m4.x, m4.y, m4.z, m4.w};
            #pragma unroll
            for (int j = 0; j < 4; ++j) {
                // valid = mask && !isnan(p) && !isnan(t)  (x!=x is the NaN test)
                bool valid = (me[j] != 0) && !(pe[j] != pe[j]) && !(te[j] != te[j]);
                float d  = pe[j] - te[j];
                float d2 = valid ? d * d : 0.f;
                ssq += d2;
                fn  += valid ? 1.f : 0.f;
                if (valid) { tpk = fmaxf(tpk, te[j]); ppk = fmaxf(ppk, pe[j]); }
                tenc[it * 4 + j] = valid ? te[j] : -INFINITY; // static index
                d2v [it * 4 + j] = d2;
            }
            // Pin staged values into VGPRs (proven: VGPR 36->52, absmax 0).
            asm volatile("" : "+v"(tenc[it*4+0]), "+v"(tenc[it*4+1]),
                              "+v"(tenc[it*4+2]), "+v"(tenc[it*4+3]),
                              "+v"(d2v [it*4+0]), "+v"(d2v [it*4+1]),
                              "+v"(d2v [it*4+2]), "+v"(d2v [it*4+3]));
        }

        ssq = waveSum(ssq); fn = waveSum(fn);
        tpk = waveMax(tpk); ppk = waveMax(ppk);
        if (lane == 0) { red[wid][0] = fn; red[wid][1] = ssq; red[wid][2] = tpk; red[wid][3] = ppk; }
        __syncthreads();

        float fnT = 0.f, ssqT = 0.f, tpkT = -INFINITY, ppkT = -INFINITY;
        #pragma unroll
        for (int w = 0; w < NWAVE; ++w) {
            fnT  += red[w][0];
            ssqT += red[w][1];
            tpkT  = fmaxf(tpkT, red[w][2]);
            ppkT  = fmaxf(ppkT, red[w][3]);
        }

        // ---- pass 2: high subset, from pinned registers ----
        // ref: high = valid & (t_peak<=0 ? true : t >= 0.8*t_peak)
        const bool  tpos = tpkT > 0.f;
        const float thr  = tpkT * 0.8f;
        float nh = 0.f, ssqh = 0.f;
        #pragma unroll
        for (int k = 0; k < VEC * 4; ++k) {
            bool hi = tpos ? (tenc[k] >= thr) : (tenc[k] > -INFINITY);
            nh   += hi ? 1.f : 0.f;
            ssqh += hi ? d2v[k] : 0.f;
        }
        nh = waveSum(nh); ssqh = waveSum(ssqh);
        __syncthreads(); // all reads of red (pass-1 partials) done before reuse
        if (lane == 0) { red[wid][0] = nh; red[wid][1] = ssqh; }
        __syncthreads();

        if (tid == 0) {
            float nht = 0.f, ssqht = 0.f;
            #pragma unroll
            for (int w = 0; w < NWAVE; ++w) { nht += red[w][0]; ssqht += red[w][1]; }
            float overall = (fnT > 0.f) ? sqrtf(ssqT  / fmaxf(fnT, 1.f)) : 0.f;
            float high_r  = (nht > 0.f) ? sqrtf(ssqht / fmaxf(nht, 1.f)) : 0.f;
            float peak_e  = (fnT > 0.f) ? fabsf(ppkT - tpkT) : 0.f;
            losssum += 0.5f * overall + 2.0f * peak_e + 1.0f * high_r;
        }
        __syncthreads(); // red reused next row
    }

    if (tid == 0) partial[blockIdx.x] = losssum; // contention-free, no atomic
}

// 512 partials -> mean loss. One 512-thread block.
__global__ __launch_bounds__(512) void flood_loss_reduce(
    const float* __restrict__ partial, float* __restrict__ out, float invB, int n)
{
    __shared__ float s[8];
    const int tid  = threadIdx.x;
    const int wid  = tid >> 6;
    const int lane = tid & 63;
    float x = (tid < n) ? partial[tid] : 0.f;
    x = waveSum(x);
    if (lane == 0) s[wid] = x;
    __syncthreads();
    if (tid == 0) {
        float tot = 0.f;
        #pragma unroll
        for (int w = 0; w < 8; ++w) tot += s[w];
        out[0] = tot * invB; // overwrite: no memset needed
    }
}

extern "C" void kernel_launch(void* const* d_in, const int* in_sizes, int n_in,
                              void* d_out, int out_size, void* d_ws, size_t ws_size,
                              hipStream_t stream) {
    const float* P = (const float*)d_in[0];
    const float* T = (const float*)d_in[1];
    const int*   M = (const int*)d_in[2];
    float* out = (float*)d_out;
    float* partial = (float*)d_ws; // 512 floats, fully overwritten each call
    const int B    = in_sizes[0] / S_LEN;   // 2048
    const int NBLK = B / ROWS_PER_BLK;      // 512

    flood_loss_rows<<<NBLK, BLK, 0, stream>>>(P, T, M, partial);
    flood_loss_reduce<<<1, 512, 0, stream>>>(partial, out, 1.0f / (float)B, NBLK);
}